// Round 1
// baseline (329.794 us; speedup 1.0000x reference)
//
#include <hip/hip_runtime.h>

// SO3 tensor product, lmax=2: out[n,o,f] = sum_k cg[k]*x1[n,i1[k],f]*x2[n,i2[k],f]
// N_ATOMS=30000, S=9, N_FEAT=128, nnz ~ 83.
//
// Strategy: scatter sparse CG to dense C[9][9][9] in d_ws (setup kernel), then a
// fully-unrolled main kernel with COMPILE-TIME pruning of the 729 triples via the
// real-SH selection rules (exactly the 83 structurally-nonzero triples). All
// register-array indexing is static => no dynamic-index scratch/cndmask chains.

#define NS 9
#define NF 128
#define NF4 32  // NF/4

// l and m for each of the 9 spherical-harmonic slots (l=0; l=1 m=-1..1; l=2 m=-2..2)
constexpr int LQ[9] = {0, 1, 1, 1, 2, 2, 2, 2, 2};
constexpr int MQ[9] = {0, -1, 0, 1, -2, -1, 0, 1, 2};

// Real-SH CG nonzero structure:
//  - triangle: |l1-l2| <= l3 <= l1+l2
//  - parity:   l1+l2+l3 even   (reference's pmask)
//  - |m3| in { |m1|+|m2|, ||m1|-|m2|| }
//  - sin/cos type: (m<0 == sin). cos*cos->cos, sin*sin->cos, mixed->sin.
constexpr bool cg_compat(int A, int B, int O) {
  const int l1 = LQ[A], l2 = LQ[B], l3 = LQ[O];
  const int m1 = MQ[A], m2 = MQ[B], m3 = MQ[O];
  const int lo = (l1 > l2) ? (l1 - l2) : (l2 - l1);
  if (l3 < lo || l3 > l1 + l2) return false;
  if ((l1 + l2 + l3) & 1) return false;
  const int u = (m1 < 0) ? -m1 : m1;
  const int v = (m2 < 0) ? -m2 : m2;
  const int w = (m3 < 0) ? -m3 : m3;
  const int d = (u > v) ? (u - v) : (v - u);
  if (!(w == u + v || w == d)) return false;
  const bool mixed = (m1 < 0) != (m2 < 0);
  if (mixed != (m3 < 0)) return false;
  return true;
}

__global__ void build_dense_cg(const float* __restrict__ cg,
                               const int* __restrict__ i1,
                               const int* __restrict__ i2,
                               const int* __restrict__ io,
                               int nnz, float* __restrict__ C) {
  const int t = threadIdx.x;
  for (int i = t; i < NS * NS * NS; i += blockDim.x) C[i] = 0.0f;
  __syncthreads();
  for (int k = t; k < nnz; k += blockDim.x) {
    C[(i1[k] * NS + i2[k]) * NS + io[k]] = cg[k];
  }
}

__global__ __launch_bounds__(256) void so3_tp_kernel(
    const float4* __restrict__ x1, const float4* __restrict__ x2,
    const float* __restrict__ C, float4* __restrict__ out, int total) {
  const int tid = blockIdx.x * 256 + threadIdx.x;
  if (tid >= total) return;
  const int atom = tid >> 5;   // / NF4
  const int f4 = tid & 31;     // % NF4

  const float4* ap = x1 + (size_t)atom * NS * NF4 + f4;
  const float4* bp = x2 + (size_t)atom * NS * NF4 + f4;

  float4 a[NS], b[NS];
#pragma unroll
  for (int s = 0; s < NS; s++) {
    a[s] = ap[s * NF4];
    b[s] = bp[s * NF4];
  }

  float4 acc[NS];
#pragma unroll
  for (int s = 0; s < NS; s++) acc[s] = make_float4(0.f, 0.f, 0.f, 0.f);

#pragma unroll
  for (int ia = 0; ia < NS; ia++) {
#pragma unroll
    for (int ib = 0; ib < NS; ib++) {
      // shared across all valid outputs for this (ia,ib); DCE'd if none valid
      const float tx = a[ia].x * b[ib].x;
      const float ty = a[ia].y * b[ib].y;
      const float tz = a[ia].z * b[ib].z;
      const float tw = a[ia].w * b[ib].w;
#pragma unroll
      for (int o = 0; o < NS; o++) {
        if (cg_compat(ia, ib, o)) {
          const float c = C[(ia * NS + ib) * NS + o];  // uniform addr -> s_load
          acc[o].x = fmaf(c, tx, acc[o].x);
          acc[o].y = fmaf(c, ty, acc[o].y);
          acc[o].z = fmaf(c, tz, acc[o].z);
          acc[o].w = fmaf(c, tw, acc[o].w);
        }
      }
    }
  }

  float4* op = out + (size_t)atom * NS * NF4 + f4;
#pragma unroll
  for (int s = 0; s < NS; s++) op[s * NF4] = acc[s];
}

extern "C" void kernel_launch(void* const* d_in, const int* in_sizes, int n_in,
                              void* d_out, int out_size, void* d_ws, size_t ws_size,
                              hipStream_t stream) {
  const float* x1 = (const float*)d_in[0];
  const float* x2 = (const float*)d_in[1];
  const float* cg = (const float*)d_in[2];
  const int* i1 = (const int*)d_in[3];
  const int* i2 = (const int*)d_in[4];
  const int* io = (const int*)d_in[5];

  const int nnz = in_sizes[2];
  const int natoms = in_sizes[0] / (NS * NF);
  float* C = (float*)d_ws;  // 729 floats of scratch (re-poisoned every call; we rewrite it)

  build_dense_cg<<<1, 256, 0, stream>>>(cg, i1, i2, io, nnz, C);

  const int total = natoms * NF4;
  const int blocks = (total + 255) / 256;
  so3_tp_kernel<<<blocks, 256, 0, stream>>>((const float4*)x1, (const float4*)x2, C,
                                            (float4*)d_out, total);
}